// Round 1
// 209.012 us; speedup vs baseline: 1.2177x; 1.2177x over previous
//
#include <hip/hip_runtime.h>
#include <float.h>

#define DIM      512
#define NCLS     21
#define MARGIN_V 5.0f
#define ROWS_PB  64             // rows per block (one row per lane, shared by all waves)
#define NWAVES   8              // waves per block; each owns a 64-float d-slice
#define DSLICE   (DIM / NWAVES) // 64
#define DC       16             // d-chunk (floats) staged per stage
#define NSTAGE   (DSLICE / DC)  // 4
#define LPAD     (DC + 1)       // 17: odd stride -> conflict-free b32 LDS
#define TILEF    (ROWS_PB * LPAD)  // 1088 floats per wave tile (4352 B)
#define CST      (NCLS + 1)     // combine stride 22 (2-way conflicts = free)

// Kernel 1: halfc2[c] = 0.5 * ||centers[c]||^2  -> d_ws
__global__ __launch_bounds__(64)
void center_norm_kernel(const float* __restrict__ centers,
                        float* __restrict__ halfc2) {
    const int c = blockIdx.x;
    const int t = threadIdx.x;
    float s = 0.f;
#pragma unroll
    for (int i = 0; i < DIM / 64; ++i) {
        float v = centers[c * DIM + i * 64 + t];
        s = fmaf(v, v, s);
    }
#pragma unroll
    for (int off = 32; off > 0; off >>= 1)
        s += __shfl_down(s, off, 64);
    if (t == 0) halfc2[c] = 0.5f * s;
}

// Kernel 2: 8 waves/block, wave w computes partial dots over d in [w*64, w*64+64)
// for the same 64 rows. Wave-private LDS tile -> NO __syncthreads in the main
// loop (intra-wave DS ordering + lgkmcnt suffice), so global prefetch is never
// drained by a barrier. Cross-wave combine via LDS tree at the end.
__global__ __launch_bounds__(512, 8)
void tcl_main_kernel(const float* __restrict__ feat,
                     const float* __restrict__ centers,
                     const int* __restrict__ labels,
                     const float* __restrict__ halfc2,
                     float* __restrict__ out) {
    __shared__ float lds[NWAVES * TILEF];   // 8704 floats = 34816 B/block -> 4 blocks/CU

    const int tid  = threadIdx.x;
    // wave id is uniform within the wave; force it scalar so the center
    // addressing below stays wave-uniform -> s_load (SGPR-operand FMAs).
    const int w    = __builtin_amdgcn_readfirstlane(tid >> 6);
    const int t    = tid & 63;
    const int row0 = blockIdx.x * ROWS_PB;

    float* mytile = &lds[w * TILEF];

    float acc[NCLS];
#pragma unroll
    for (int c = 0; c < NCLS; ++c) acc[c] = 0.f;

    const float4* fbase = reinterpret_cast<const float4*>(feat);
    // Stage layout: per stage this wave loads 64 rows x 16 floats = 256 float4.
    // Lane t -> rsub = t>>2 (row within 16-row group), j4 = t&3.
    // 4 consecutive lanes read one aligned 64-B line (w*256B + s*64B offset
    // within the row) -> 16 fully-consumed cache lines per instruction.
    const int rsub = t >> 2;
    const int j4   = t & 3;
    const size_t gbase = (size_t)(row0 + rsub) * (DIM / 4)
                       + (size_t)w * (DSLICE / 4) + j4;

    float4 pre[4];
#pragma unroll
    for (int i = 0; i < 4; ++i)
        pre[i] = fbase[gbase + (size_t)i * 16 * (DIM / 4)];   // stage 0

    const int wbase = rsub * LPAD + j4 * 4;

#pragma unroll 1
    for (int s = 0; s < NSTAGE; ++s) {
        // write prefetched stage into this wave's private padded tile
#pragma unroll
        for (int i = 0; i < 4; ++i) {
            int b = i * 16 * LPAD + wbase;
            mytile[b + 0] = pre[i].x;
            mytile[b + 1] = pre[i].y;
            mytile[b + 2] = pre[i].z;
            mytile[b + 3] = pre[i].w;
        }
        // issue next stage's global loads; consumed one full stage later
        if (s + 1 < NSTAGE) {
#pragma unroll
            for (int i = 0; i < 4; ++i)
                pre[i] = fbase[gbase + (size_t)i * 16 * (DIM / 4)
                               + (size_t)(s + 1) * (DC / 4)];
        }
        // compute: lane t owns row t; center reads are wave-uniform -> s_load
        const int dbase = w * DSLICE + s * DC;
#pragma unroll 2
        for (int jj = 0; jj < DC; jj += 4) {
            float f0 = mytile[t * LPAD + jj + 0];
            float f1 = mytile[t * LPAD + jj + 1];
            float f2 = mytile[t * LPAD + jj + 2];
            float f3 = mytile[t * LPAD + jj + 3];
#pragma unroll
            for (int c = 0; c < NCLS; ++c) {
                const float* cp = &centers[c * DIM + dbase + jj];
                acc[c] = fmaf(f0, cp[0],
                          fmaf(f1, cp[1],
                           fmaf(f2, cp[2],
                            fmaf(f3, cp[3], acc[c]))));
            }
        }
    }

    // ---- cross-wave combine: 8 -> 4 -> 2 -> 1, reusing stage LDS ----
    float* comb = lds;   // 4 slots x 64 rows x 22 floats = 22528 B <= 34816 B
    __syncthreads();
    if (w >= 4) {
        float* p = &comb[((w - 4) * ROWS_PB + t) * CST];
#pragma unroll
        for (int c = 0; c < NCLS; ++c) p[c] = acc[c];
    }
    __syncthreads();
    if (w < 4) {
        const float* p = &comb[(w * ROWS_PB + t) * CST];
#pragma unroll
        for (int c = 0; c < NCLS; ++c) acc[c] += p[c];
    }
    __syncthreads();
    if (w == 2 || w == 3) {
        float* p = &comb[((w - 2) * ROWS_PB + t) * CST];
#pragma unroll
        for (int c = 0; c < NCLS; ++c) p[c] = acc[c];
    }
    __syncthreads();
    if (w < 2) {
        const float* p = &comb[(w * ROWS_PB + t) * CST];
#pragma unroll
        for (int c = 0; c < NCLS; ++c) acc[c] += p[c];
    }
    __syncthreads();
    if (w == 1) {
        float* p = &comb[t * CST];
#pragma unroll
        for (int c = 0; c < NCLS; ++c) p[c] = acc[c];
    }
    __syncthreads();
    if (w == 0) {
        const float* p = &comb[t * CST];
        const int lab = labels[row0 + t];
        float pos = 0.f, neg = FLT_MAX;
#pragma unroll
        for (int c = 0; c < NCLS; ++c) {
            float e = halfc2[c] - (acc[c] + p[c]);
            pos = (c == lab) ? e : pos;
            neg = (c == lab) ? neg : fminf(neg, e);
        }
        float v = fmaxf(pos + MARGIN_V - neg, 0.f);
#pragma unroll
        for (int off = 32; off > 0; off >>= 1)
            v += __shfl_down(v, off, 64);
        if (t == 0) atomicAdd(out, v * (1.0f / 65536.f));
    }
}

extern "C" void kernel_launch(void* const* d_in, const int* in_sizes, int n_in,
                              void* d_out, int out_size, void* d_ws, size_t ws_size,
                              hipStream_t stream) {
    const float* feat    = (const float*)d_in[0];   // (65536, 512) fp32
    const float* centers = (const float*)d_in[1];   // (21, 512) fp32
    const int*   labels  = (const int*)d_in[2];     // (65536,) int
    float* out    = (float*)d_out;                  // scalar loss
    float* halfc2 = (float*)d_ws;                   // 21 floats scratch

    hipMemsetAsync(d_out, 0, (size_t)out_size * sizeof(float), stream);
    center_norm_kernel<<<NCLS, 64, 0, stream>>>(centers, halfc2);

    const int nblocks = 65536 / ROWS_PB;            // 1024 blocks x 8 waves = 8192 waves
    tcl_main_kernel<<<nblocks, 512, 0, stream>>>(feat, centers, labels, halfc2, out);
}

// Round 2
// 204.614 us; speedup vs baseline: 1.2439x; 1.0215x over previous
//
#include <hip/hip_runtime.h>
#include <float.h>

#define DIM      512
#define NCLS     21
#define MARGIN_V 5.0f
#define ROWS_PB  64             // rows per block (one row per lane, shared by all waves)
#define NWAVES   8              // waves per block; each owns a 64-float d-slice
#define DSLICE   (DIM / NWAVES) // 64
#define DC       16             // d-chunk (floats) staged per stage
#define NSTAGE   (DSLICE / DC)  // 4
#define LPAD     (DC + 1)       // 17: odd stride -> conflict-free b32 LDS
#define TILEF    (ROWS_PB * LPAD)  // 1088 floats per wave tile (4352 B)
#define CLDSF    (NCLS * DIM)   // 10752 floats: full centers table in LDS (43008 B)
#define CST      (NCLS + 1)     // combine stride 22 (2-way conflicts = free)

// Kernel 1: halfc2[c] = 0.5 * ||centers[c]||^2  -> d_ws
__global__ __launch_bounds__(64)
void center_norm_kernel(const float* __restrict__ centers,
                        float* __restrict__ halfc2) {
    const int c = blockIdx.x;
    const int t = threadIdx.x;
    float s = 0.f;
#pragma unroll
    for (int i = 0; i < DIM / 64; ++i) {
        float v = centers[c * DIM + i * 64 + t];
        s = fmaf(v, v, s);
    }
#pragma unroll
    for (int off = 32; off > 0; off >>= 1)
        s += __shfl_down(s, off, 64);
    if (t == 0) halfc2[c] = 0.5f * s;
}

// Kernel 2: 8 waves/block, wave w computes partial dots over d in [w*64, w*64+64).
// Centers live in LDS (staged once per block) and are read as uniform-address
// ds_read_b128 broadcasts -> no scalar-load convoy, no SGPR pressure.
// Feature tiles stay wave-private (barrier-free main loop, prefetch in VGPRs).
__global__ __launch_bounds__(512, 4)
void tcl_main_kernel(const float* __restrict__ feat,
                     const float* __restrict__ centers,
                     const int* __restrict__ labels,
                     const float* __restrict__ halfc2,
                     float* __restrict__ out) {
    __shared__ float lds[CLDSF + NWAVES * TILEF];   // 19456 floats = 77824 B -> 2 blocks/CU

    const int tid  = threadIdx.x;
    // wave id scalarized (uniform addressing for tile base)
    const int w    = __builtin_amdgcn_readfirstlane(tid >> 6);
    const int t    = tid & 63;
    const int row0 = blockIdx.x * ROWS_PB;

    float acc[NCLS];
#pragma unroll
    for (int c = 0; c < NCLS; ++c) acc[c] = 0.f;

    const float4* fbase = reinterpret_cast<const float4*>(feat);
    // Per stage this wave loads 64 rows x 16 floats = 256 float4.
    // Lane t -> rsub = t>>2 (row within 16-row group), j4 = t&3.
    const int rsub = t >> 2;
    const int j4   = t & 3;
    const size_t gbase = (size_t)(row0 + rsub) * (DIM / 4)
                       + (size_t)w * (DSLICE / 4) + j4;

    // issue stage-0 feature loads first so they fly during center staging
    float4 pre[4];
#pragma unroll
    for (int i = 0; i < 4; ++i)
        pre[i] = fbase[gbase + (size_t)i * 16 * (DIM / 4)];
    __builtin_amdgcn_sched_barrier(0);

    // stage full centers table into LDS (block-cooperative, float4)
    {
        const float4* c4 = reinterpret_cast<const float4*>(centers);
        float4* l4 = reinterpret_cast<float4*>(lds);
#pragma unroll
        for (int i = 0; i < (CLDSF / 4 + 511) / 512; ++i) {
            int idx = i * 512 + tid;
            if (idx < CLDSF / 4) l4[idx] = c4[idx];
        }
    }

    float* mytile = &lds[CLDSF + w * TILEF];
    const int wbase = rsub * LPAD + j4 * 4;

    __syncthreads();   // centers ready; main loop below is barrier-free

#pragma unroll 1
    for (int s = 0; s < NSTAGE; ++s) {
        // write prefetched stage into this wave's private padded tile
#pragma unroll
        for (int i = 0; i < 4; ++i) {
            int b = i * 16 * LPAD + wbase;
            mytile[b + 0] = pre[i].x;
            mytile[b + 1] = pre[i].y;
            mytile[b + 2] = pre[i].z;
            mytile[b + 3] = pre[i].w;
        }
        // issue next stage's global loads; pin them here (don't let them sink)
        if (s + 1 < NSTAGE) {
#pragma unroll
            for (int i = 0; i < 4; ++i)
                pre[i] = fbase[gbase + (size_t)i * 16 * (DIM / 4)
                               + (size_t)(s + 1) * (DC / 4)];
        }
        __builtin_amdgcn_sched_barrier(0);

        // compute: lane t owns row t; centers via uniform LDS broadcast b128
        const int dbase = w * DSLICE + s * DC;
#pragma unroll 2
        for (int jj = 0; jj < DC; jj += 4) {
            float f0 = mytile[t * LPAD + jj + 0];
            float f1 = mytile[t * LPAD + jj + 1];
            float f2 = mytile[t * LPAD + jj + 2];
            float f3 = mytile[t * LPAD + jj + 3];
            // 3 chunks of 7 classes bound VGPR liveness (~28 regs of centers)
#pragma unroll
            for (int ch = 0; ch < 3; ++ch) {
                float4 cv[7];
#pragma unroll
                for (int k = 0; k < 7; ++k)
                    cv[k] = *reinterpret_cast<const float4*>(
                        &lds[(ch * 7 + k) * DIM + dbase + jj]);
#pragma unroll
                for (int k = 0; k < 7; ++k) {
                    int c = ch * 7 + k;
                    acc[c] = fmaf(f0, cv[k].x,
                              fmaf(f1, cv[k].y,
                               fmaf(f2, cv[k].z,
                                fmaf(f3, cv[k].w, acc[c]))));
                }
            }
        }
    }

    // ---- cross-wave combine: 8 -> 4 -> 2 -> 1, reusing LDS ----
    float* comb = lds;   // 4 slots x 64 rows x 22 floats = 22528 B <= 77824 B
    __syncthreads();
    if (w >= 4) {
        float* p = &comb[((w - 4) * ROWS_PB + t) * CST];
#pragma unroll
        for (int c = 0; c < NCLS; ++c) p[c] = acc[c];
    }
    __syncthreads();
    if (w < 4) {
        const float* p = &comb[(w * ROWS_PB + t) * CST];
#pragma unroll
        for (int c = 0; c < NCLS; ++c) acc[c] += p[c];
    }
    __syncthreads();
    if (w == 2 || w == 3) {
        float* p = &comb[((w - 2) * ROWS_PB + t) * CST];
#pragma unroll
        for (int c = 0; c < NCLS; ++c) p[c] = acc[c];
    }
    __syncthreads();
    if (w < 2) {
        const float* p = &comb[(w * ROWS_PB + t) * CST];
#pragma unroll
        for (int c = 0; c < NCLS; ++c) acc[c] += p[c];
    }
    __syncthreads();
    if (w == 1) {
        float* p = &comb[t * CST];
#pragma unroll
        for (int c = 0; c < NCLS; ++c) p[c] = acc[c];
    }
    __syncthreads();
    if (w == 0) {
        const float* p = &comb[t * CST];
        const int lab = labels[row0 + t];
        float pos = 0.f, neg = FLT_MAX;
#pragma unroll
        for (int c = 0; c < NCLS; ++c) {
            float e = halfc2[c] - (acc[c] + p[c]);
            pos = (c == lab) ? e : pos;
            neg = (c == lab) ? neg : fminf(neg, e);
        }
        float v = fmaxf(pos + MARGIN_V - neg, 0.f);
#pragma unroll
        for (int off = 32; off > 0; off >>= 1)
            v += __shfl_down(v, off, 64);
        if (t == 0) atomicAdd(out, v * (1.0f / 65536.f));
    }
}

extern "C" void kernel_launch(void* const* d_in, const int* in_sizes, int n_in,
                              void* d_out, int out_size, void* d_ws, size_t ws_size,
                              hipStream_t stream) {
    const float* feat    = (const float*)d_in[0];   // (65536, 512) fp32
    const float* centers = (const float*)d_in[1];   // (21, 512) fp32
    const int*   labels  = (const int*)d_in[2];     // (65536,) int
    float* out    = (float*)d_out;                  // scalar loss
    float* halfc2 = (float*)d_ws;                   // 21 floats scratch

    hipMemsetAsync(d_out, 0, (size_t)out_size * sizeof(float), stream);
    center_norm_kernel<<<NCLS, 64, 0, stream>>>(centers, halfc2);

    const int nblocks = 65536 / ROWS_PB;            // 1024 blocks x 8 waves
    tcl_main_kernel<<<nblocks, 512, 0, stream>>>(feat, centers, labels, halfc2, out);
}